// Round 12
// baseline (859.762 us; speedup 1.0000x reference)
//
#include <hip/hip_runtime.h>
#include <stdint.h>

#define BB 8
#define NN 4096
#define CC 64
#define MM 1024
#define EE (BB*MM)   // 8192 centroids
#define KK 64        // max neighbors
#define F3 256       // output channels
#define SM 104       // msg LDS stride (elements)
#define SH 136       // h LDS stride (elements)
#define CAP 768      // candidate buffer

typedef __bf16 bf16x8 __attribute__((ext_vector_type(8)));
typedef float floatx4 __attribute__((ext_vector_type(4)));

// ---- wave64 reductions via DPP (round-3-verified) ----
#define DPP_MAXSTEP(ctrl, rmask) { \
    unsigned o = (unsigned)__builtin_amdgcn_update_dpp(0, (int)v, ctrl, rmask, 0xf, false); \
    v = v > o ? v : o; }
__device__ __forceinline__ unsigned wave_umax_u32(unsigned v) {
  DPP_MAXSTEP(0x111, 0xf)
  DPP_MAXSTEP(0x112, 0xf)
  DPP_MAXSTEP(0x114, 0xf)
  DPP_MAXSTEP(0x118, 0xf)
  DPP_MAXSTEP(0x142, 0xa)
  DPP_MAXSTEP(0x143, 0xc)
  return (unsigned)__builtin_amdgcn_readlane((int)v, 63);
}
#define DPP_MINSTEP(ctrl, rmask) { \
    unsigned o = (unsigned)__builtin_amdgcn_update_dpp((int)0xffffffffu, (int)v, ctrl, rmask, 0xf, false); \
    v = v < o ? v : o; }
__device__ __forceinline__ unsigned wave_umin_u32(unsigned v) {
  DPP_MINSTEP(0x111, 0xf)
  DPP_MINSTEP(0x112, 0xf)
  DPP_MINSTEP(0x114, 0xf)
  DPP_MINSTEP(0x118, 0xf)
  DPP_MINSTEP(0x142, 0xa)
  DPP_MINSTEP(0x143, 0xc)
  return (unsigned)__builtin_amdgcn_readlane((int)v, 63);
}

// ---- MLP item body (round-3-verified numerics; r5/r11-verified refactor) ----
__device__ __forceinline__ void mlp_item(
    int e, int b, int t,
    const float* __restrict__ x, const float4* __restrict__ pos4,
    const float* __restrict__ ctr, const int* __restrict__ fpsIdx,
    const __bf16* __restrict__ W1t, const __bf16* __restrict__ W2t,
    const __bf16* __restrict__ W3t,
    const float* __restrict__ b1, const float* __restrict__ b2,
    const float* __restrict__ b3,
    float* __restrict__ outX, float* __restrict__ outP,
    float* __restrict__ outB, float* __restrict__ outS,
    __bf16* sMsg, __bf16* sH, int* sSel, int* sCnt) {
  // caller must have set *sCnt = 0 and issued __syncthreads()
  unsigned long long* sDI = (unsigned long long*)sMsg;  // [CAP] packed (d2bits<<32 | idx)
  const int lane = t & 63, wv = t >> 6;

  const float cx = ctr[(long)e * 3 + 0];
  const float cy = ctr[(long)e * 3 + 1];
  const float cz = ctr[(long)e * 3 + 2];
  if (t < 3) outP[(long)e * 3 + t] = ctr[(long)e * 3 + t];
  if (t == 3) { outB[e] = (float)b; outS[e] = (float)(b * NN + fpsIdx[e]); }
  const float R2 = (float)(0.2 * 0.2);

  // Phase A: scan 4096 points; ballot-compact candidates to LDS.
#pragma unroll
  for (int q = 0; q < NN / 512; ++q) {
    const int p = t + q * 512;
    const float4 P = pos4[b * NN + p];
    const float dx = __fsub_rn(cx, P.x);
    const float dy = __fsub_rn(cy, P.y);
    const float dz = __fsub_rn(cz, P.z);
    const float d2 = __fadd_rn(__fadd_rn(__fmul_rn(dx, dx), __fmul_rn(dy, dy)), __fmul_rn(dz, dz));
    const bool v = d2 < R2;
    const unsigned long long mask = __ballot(v);
    int wbase = 0;
    if (lane == 0 && mask) wbase = atomicAdd(sCnt, (int)__popcll(mask));
    wbase = __shfl(wbase, 0);
    if (v) {
      const int off = wbase + (int)__popcll(mask & ((1ull << lane) - 1ull));
      if (off < CAP)
        sDI[off] = ((unsigned long long)__float_as_uint(d2) << 32) | (unsigned)p;
    }
  }
  __syncthreads();
  int cnt = *sCnt; cnt = cnt > CAP ? CAP : cnt;
  const int nsel = cnt < KK ? cnt : KK;

  // Phase B: parallel rank selection.
  for (int i = t; i < cnt; i += 512) {
    const unsigned long long my = sDI[i];
    int rank = 0;
#pragma unroll 8
    for (int j = 0; j < cnt; ++j) rank += (sDI[j] < my) ? 1 : 0;
    if (rank < KK) sSel[rank] = (int)(unsigned)(my & 0xffffffffu);
  }
  __syncthreads();
  cnt = nsel;

  // Phase C: stage msg tile into LDS as bf16.
  {
    const int r = t >> 3, p = t & 7;
    float4 a = make_float4(0.f, 0.f, 0.f, 0.f), c4 = a;
    if (r < cnt) {
      const float* xr = x + (long)(b * NN + sSel[r]) * CC + p * 8;
      a  = *(const float4*)xr;
      c4 = *(const float4*)(xr + 4);
    }
    __bf16 o[8] = {(__bf16)a.x, (__bf16)a.y, (__bf16)a.z, (__bf16)a.w,
                   (__bf16)c4.x, (__bf16)c4.y, (__bf16)c4.z, (__bf16)c4.w};
    *(uint4*)&sMsg[r * SM + p * 8] = *(uint4*)o;
  }
  if (t < 64) {
    const int r = t;
    __bf16 d0 = (__bf16)0.0f, d1 = (__bf16)0.0f, d2v = (__bf16)0.0f;
    if (r < cnt) {
      const float4 P = pos4[b * NN + sSel[r]];
      d0  = (__bf16)__fsub_rn(P.x, cx);
      d1  = (__bf16)__fsub_rn(P.y, cy);
      d2v = (__bf16)__fsub_rn(P.z, cz);
    }
    sMsg[r * SM + 64] = d0;
    sMsg[r * SM + 65] = d1;
    sMsg[r * SM + 66] = d2v;
    for (int c = 67; c < SM; ++c) sMsg[r * SM + c] = (__bf16)0.0f;
  }
  __syncthreads();

  const int l15 = lane & 15, quad = lane >> 4;
  // layer 1
  {
    floatx4 acc[4] = {};
    const __bf16* wrow = W1t + (wv * 16 + l15) * 96;
#pragma unroll
    for (int ks = 0; ks < 3; ++ks) {
      const bf16x8 bfrag = *(const bf16x8*)(wrow + ks * 32 + quad * 8);
#pragma unroll
      for (int mt = 0; mt < 4; ++mt) {
        const bf16x8 afrag = *(const bf16x8*)&sMsg[(mt * 16 + l15) * SM + ks * 32 + quad * 8];
        acc[mt] = __builtin_amdgcn_mfma_f32_16x16x32_bf16(afrag, bfrag, acc[mt], 0, 0, 0);
      }
    }
    const int col = wv * 16 + l15;
    const float bias = b1[col];
#pragma unroll
    for (int mt = 0; mt < 4; ++mt)
#pragma unroll
      for (int rg = 0; rg < 4; ++rg) {
        const int row = mt * 16 + quad * 4 + rg;
        float v = acc[mt][rg] + bias;
        v = v > 0.0f ? v : 0.0f;
        sH[row * SH + col] = (__bf16)v;
      }
  }
  __syncthreads();
  // layer 2 (in place on sH)
  {
    floatx4 acc[4] = {};
    const __bf16* wrow = W2t + (wv * 16 + l15) * 128;
#pragma unroll
    for (int ks = 0; ks < 4; ++ks) {
      const bf16x8 bfrag = *(const bf16x8*)(wrow + ks * 32 + quad * 8);
#pragma unroll
      for (int mt = 0; mt < 4; ++mt) {
        const bf16x8 afrag = *(const bf16x8*)&sH[(mt * 16 + l15) * SH + ks * 32 + quad * 8];
        acc[mt] = __builtin_amdgcn_mfma_f32_16x16x32_bf16(afrag, bfrag, acc[mt], 0, 0, 0);
      }
    }
    __syncthreads();
    const int col = wv * 16 + l15;
    const float bias = b2[col];
#pragma unroll
    for (int mt = 0; mt < 4; ++mt)
#pragma unroll
      for (int rg = 0; rg < 4; ++rg) {
        const int row = mt * 16 + quad * 4 + rg;
        float v = acc[mt][rg] + bias;
        v = v > 0.0f ? v : 0.0f;
        sH[row * SH + col] = (__bf16)v;
      }
  }
  __syncthreads();
  // layer 3 + fused masked max
  {
    floatx4 acc[2][4] = {};
#pragma unroll
    for (int ks = 0; ks < 4; ++ks) {
      bf16x8 afrag[4];
#pragma unroll
      for (int mt = 0; mt < 4; ++mt)
        afrag[mt] = *(const bf16x8*)&sH[(mt * 16 + l15) * SH + ks * 32 + quad * 8];
#pragma unroll
      for (int i = 0; i < 2; ++i) {
        const bf16x8 bfrag = *(const bf16x8*)(W3t + ((wv * 2 + i) * 16 + l15) * 128 + ks * 32 + quad * 8);
#pragma unroll
        for (int mt = 0; mt < 4; ++mt)
          acc[i][mt] = __builtin_amdgcn_mfma_f32_16x16x32_bf16(afrag[mt], bfrag, acc[i][mt], 0, 0, 0);
      }
    }
#pragma unroll
    for (int i = 0; i < 2; ++i) {
      const int col = (wv * 2 + i) * 16 + l15;
      const float bias = b3[col];
      float mx = 0.0f;
#pragma unroll
      for (int mt = 0; mt < 4; ++mt)
#pragma unroll
        for (int rg = 0; rg < 4; ++rg) {
          const int row = mt * 16 + quad * 4 + rg;
          float v = acc[i][mt][rg] + bias;
          v = v > 0.0f ? v : 0.0f;
          if (row < cnt) mx = fmaxf(mx, v);
        }
      mx = fmaxf(mx, __shfl_xor(mx, 16));
      mx = fmaxf(mx, __shfl_xor(mx, 32));
      if (quad == 0) outX[(long)e * F3 + col] = mx;
    }
  }
}

// ctl layout (dwords; each counter on its own 128B line); memset 2048 B:
#define CTL_PREP 0
#define CTL_PROG(g) (32*((g)+1))
#define CTL_QHEAD 320
#define CTL_DONE 352

// ---- Kernel A: grid 256, 82 KB LDS pad => 1 block/CU (r11-verified).
//      NEW vs r11: FPS waves 0-3 do ZERO global stores in the loop (winner idx
//      goes to an LDS ring); idle wave 4 batch-flushes ctr/fpsIdx every 32
//      samples and publishes progress. [HIP-compiler] __syncthreads emits
//      s_waitcnt vmcnt(0) before s_barrier, so r11's per-iter t0 stores put a
//      full L2-store drain on the FPS critical path every iteration (~165us
//      total under worker traffic). This removes it.
__global__ __launch_bounds__(512) void fps_overlap_kernel(
    const float* __restrict__ x, const float* __restrict__ pos,
    const float* __restrict__ W1, const float* __restrict__ b1,
    const float* __restrict__ W2, const float* __restrict__ b2,
    const float* __restrict__ W3, const float* __restrict__ b3,
    int* __restrict__ fpsIdx, float* __restrict__ ctr,
    __bf16* __restrict__ W1t, __bf16* __restrict__ W2t, __bf16* __restrict__ W3t,
    float4* __restrict__ pos4, unsigned* __restrict__ ctl,
    float* __restrict__ outX, float* __restrict__ outP,
    float* __restrict__ outB, float* __restrict__ outS) {
  __shared__ __align__(16) unsigned char sBuf[83968];  // 82 KB pad => exclusive CU
  __shared__ int sClaim;

  const int t = threadIdx.x;
  const int blk = blockIdx.x;

  if (blk < BB) {
    // ================= FPS producer (graph g), r3-exact 4-wave loop =================
    const int g = blk;
    float4* sP4 = (float4*)sBuf;
    unsigned long long* sRed = (unsigned long long*)(sBuf + 65536);  // [2][4] = 64 B
    int* sWin = (int*)(sBuf + 65600);                                // 64-entry ring, 256 B

    // prep slice: 94208 items over 8 blocks = 11776 each
    for (int k = g * 11776 + t; k < (g + 1) * 11776; k += 512) {
      if (k < 12288) {
        const int n = k / 96, kk = k % 96;
        W1t[k] = (kk < 67) ? (__bf16)W1[kk * 128 + n] : (__bf16)0.0f;
      } else if (k < 28672) {
        const int i = k - 12288, n = i / 128, kk = i % 128;
        W2t[i] = (__bf16)W2[kk * 128 + n];
      } else if (k < 61440) {
        const int i = k - 28672, n = i / 128, kk = i % 128;
        W3t[i] = (__bf16)W3[kk * 256 + n];
      } else {
        const int i = k - 61440;
        pos4[i] = make_float4(pos[(long)i * 3 + 0], pos[(long)i * 3 + 1],
                              pos[(long)i * 3 + 2], 0.0f);
      }
    }
    __threadfence();
    __syncthreads();
    if (t == 0)
      __hip_atomic_fetch_add(&ctl[CTL_PREP], 1u, __ATOMIC_RELEASE, __HIP_MEMORY_SCOPE_AGENT);

    __builtin_amdgcn_s_setprio(1);

    const int lane = t & 63, wv = t >> 6;    // working waves 0..3 (t<256)
    float px[16], py[16], pz[16], mind[16];
    if (t < 256) {
#pragma unroll
      for (int j = 0; j < 16; ++j) {
        const int p = t + (j << 8);
        const long base = ((long)g * NN + p) * 3;
        px[j] = pos[base + 0];
        py[j] = pos[base + 1];
        pz[j] = pos[base + 2];
        mind[j] = 1e10f;
        sP4[p] = make_float4(px[j], py[j], pz[j], 0.0f);
      }
    }
    if (t == 0) sWin[0] = 0;                 // sample 0 = point 0 (flushed in batch 0)
    __syncthreads();
    float wx = 0.f, wy = 0.f, wz = 0.f;
    if (t < 256) { const float4 w0 = sP4[0]; wx = w0.x; wy = w0.y; wz = w0.z; }
    for (int s = 1; s < MM; ++s) {
      if (t < 256) {
        // --- inner: exact r3 numerics; NO vmem in loop for waves 0-3 ---
        unsigned bb = 0u, bidx = (unsigned)t;
#pragma unroll
        for (int j = 0; j < 16; ++j) {
          const float dx = __fsub_rn(px[j], wx);
          const float dy = __fsub_rn(py[j], wy);
          const float dz = __fsub_rn(pz[j], wz);
          const float d2 = __fadd_rn(__fadd_rn(__fmul_rn(dx, dx), __fmul_rn(dy, dy)), __fmul_rn(dz, dz));
          mind[j] = fminf(mind[j], d2);
          const unsigned mb = __float_as_uint(mind[j]);
          if (mb > bb) { bb = mb; bidx = (unsigned)(t + (j << 8)); }
        }
        const unsigned maxv = wave_umax_u32(bb);
        const unsigned cand = (bb == maxv) ? bidx : 0xffffffffu;
        const unsigned widx_w = wave_umin_u32(cand);
        if (lane == 0)
          sRed[(s & 1) * 4 + wv] = ((unsigned long long)maxv << 32) | (unsigned long long)(~widx_w);
      }
      __syncthreads();
      if (t < 256) {
        unsigned long long m = sRed[(s & 1) * 4 + 0];
#pragma unroll
        for (int w = 1; w < 4; ++w) {
          const unsigned long long o = sRed[(s & 1) * 4 + w];
          m = o > m ? o : m;
        }
        const int widx = (int)(~(unsigned)m);
        const float4 wp = sP4[widx];
        wx = wp.x; wy = wp.y; wz = wp.z;
        if (t == 0) sWin[s & 63] = widx;     // LDS only; batch-flushed by wave 4
      } else if (t < 320) {
        // ---- wave 4: flush batch (s-32..s-1) once per 32 iters; off critical path ----
        if ((s & 31) == 0) {                 // s = 32, 64, ..., 992
          const int l = t - 256;
          if (l < 32) {
            const int samp = (s - 32) + l;
            const int widx = sWin[samp & 63];        // visible: written pre-B_s, disjoint slots
            const float4 wp = sP4[widx];
            const long eo = (long)g * MM + samp;
            ctr[eo * 3 + 0] = wp.x; ctr[eo * 3 + 1] = wp.y; ctr[eo * 3 + 2] = wp.z;
            fpsIdx[eo] = widx;
          }
          __threadfence();                   // wave-wide store drain before publish
          if (t == 256)
            __hip_atomic_store(&ctl[CTL_PROG(g)], (unsigned)s,
                               __ATOMIC_RELEASE, __HIP_MEMORY_SCOPE_AGENT);
        }
      }
    }
    // final batch: samples 992..1023 (sWin[1023&63] written post-B_1023)
    __syncthreads();
    if (t >= 256 && t < 320) {
      const int l = t - 256;
      if (l < 32) {
        const int samp = 992 + l;
        const int widx = sWin[samp & 63];
        const float4 wp = sP4[widx];
        const long eo = (long)g * MM + samp;
        ctr[eo * 3 + 0] = wp.x; ctr[eo * 3 + 1] = wp.y; ctr[eo * 3 + 2] = wp.z;
        fpsIdx[eo] = widx;
      }
      __threadfence();
      if (t == 256)
        __hip_atomic_store(&ctl[CTL_PROG(g)], 1024u,
                           __ATOMIC_RELEASE, __HIP_MEMORY_SCOPE_AGENT);
    }
    __syncthreads();
    if (t == 0)
      __hip_atomic_fetch_add(&ctl[CTL_DONE], 1u, __ATOMIC_RELEASE, __HIP_MEMORY_SCOPE_AGENT);
    return;
  }

  // ================= persistent MLP worker (exclusive CU) =================
  {
    __bf16* sMsg = (__bf16*)sBuf;
    __bf16* sH   = (__bf16*)(sBuf + 13312);
    int* sSel    = (int*)(sBuf + 30720);
    int* sCnt    = (int*)(sBuf + 30976);

    if (t == 0) {  // weights/pos4 gate (once)
      while (__hip_atomic_load(&ctl[CTL_PREP], __ATOMIC_ACQUIRE, __HIP_MEMORY_SCOPE_AGENT) < (unsigned)BB)
        __builtin_amdgcn_s_sleep(8);
    }
    __syncthreads();

    for (;;) {
      if (t == 0) {
        unsigned c;
        const unsigned dn = __hip_atomic_load(&ctl[CTL_DONE], __ATOMIC_ACQUIRE, __HIP_MEMORY_SCOPE_AGENT);
        if (dn >= (unsigned)BB) c = EE;          // FPS done: stop claiming; drain finishes rest
        else c = __hip_atomic_fetch_add(&ctl[CTL_QHEAD], 1u, __ATOMIC_RELAXED, __HIP_MEMORY_SCOPE_AGENT);
        sClaim = (int)c;
      }
      __syncthreads();
      const int c = sClaim;
      if (c >= EE) return;
      const int g = c & 7, sidx = c >> 3;        // interleave across graphs = production order
      const int e = g * MM + sidx;
      if (t == 0) {
        while (__hip_atomic_load(&ctl[CTL_PROG(g)], __ATOMIC_ACQUIRE, __HIP_MEMORY_SCOPE_AGENT)
               <= (unsigned)sidx)
          __builtin_amdgcn_s_sleep(8);
        *sCnt = 0;
      }
      __syncthreads();
      mlp_item(e, g, t, x, pos4, ctr, fpsIdx, W1t, W2t, W3t, b1, b2, b3,
               outX, outP, outB, outS, sMsg, sH, sSel, sCnt);
      // loop-top barrier re-joins all threads before LDS reuse
    }
  }
}

// ---- Kernel B: drain remaining items (runs after A completes; no spins) ----
__global__ __launch_bounds__(512) void drain_kernel(
    const float* __restrict__ x, const float4* __restrict__ pos4,
    const float* __restrict__ ctr, const int* __restrict__ fpsIdx,
    const __bf16* __restrict__ W1t, const __bf16* __restrict__ W2t,
    const __bf16* __restrict__ W3t,
    const float* __restrict__ b1, const float* __restrict__ b2,
    const float* __restrict__ b3, unsigned* __restrict__ ctl,
    float* __restrict__ outX, float* __restrict__ outP,
    float* __restrict__ outB, float* __restrict__ outS) {
  __shared__ __align__(16) __bf16 sMsg[64 * SM];
  __shared__ __align__(16) __bf16 sH[64 * SH];
  __shared__ int sSel[KK];
  __shared__ int sCnt;
  __shared__ int sClaim;
  const int t = threadIdx.x;

  if (t == 0) {
    unsigned c = __hip_atomic_load(&ctl[CTL_QHEAD], __ATOMIC_RELAXED, __HIP_MEMORY_SCOPE_AGENT);
    if (c < (unsigned)EE)   // shortcut avoids atomic herd once queue exhausted
      c = __hip_atomic_fetch_add(&ctl[CTL_QHEAD], 1u, __ATOMIC_RELAXED, __HIP_MEMORY_SCOPE_AGENT);
    sClaim = (int)c;
    sCnt = 0;
  }
  __syncthreads();
  const int c = sClaim;
  if (c >= EE) return;
  const int g = c & 7, sidx = c >> 3;
  mlp_item(g * MM + sidx, g, t, x, pos4, ctr, fpsIdx, W1t, W2t, W3t, b1, b2, b3,
           outX, outP, outB, outS, sMsg, sH, sSel, &sCnt);
}

extern "C" void kernel_launch(void* const* d_in, const int* in_sizes, int n_in,
                              void* d_out, int out_size, void* d_ws, size_t ws_size,
                              hipStream_t stream) {
  const float* x   = (const float*)d_in[0];
  const float* pos = (const float*)d_in[1];
  const float* W1  = (const float*)d_in[4];
  const float* b1  = (const float*)d_in[5];
  const float* W2  = (const float*)d_in[6];
  const float* b2  = (const float*)d_in[7];
  const float* W3  = (const float*)d_in[8];
  const float* b3  = (const float*)d_in[9];

  // Workspace layout (~781 KB)
  char* ws = (char*)d_ws;
  int*    fpsIdx = (int*)(ws);                 // 32768              (ends 32768)
  float*  ctr    = (float*)(ws + 32768);       // 98304              (ends 131072)
  __bf16* W1t    = (__bf16*)(ws + 131072);     // 24576              (ends 155648)
  __bf16* W2t    = (__bf16*)(ws + 155648);     // 32768              (ends 188416)
  __bf16* W3t    = (__bf16*)(ws + 188416);     // 65536              (ends 253952)
  float4* pos4   = (float4*)(ws + 253952);     // 524288             (ends 778240)
  unsigned* ctl  = (unsigned*)(ws + 778240);   // 2048               (ends 780288)

  float* outX = (float*)d_out;                 // [8192,256]
  float* outP = outX + (long)EE * F3;          // [8192,3]
  float* outB = outP + (long)EE * 3;           // [8192]
  float* outS = outB + EE;                     // [8192]

  hipMemsetAsync(ctl, 0, 2048, stream);
  fps_overlap_kernel<<<256, 512, 0, stream>>>(x, pos, W1, b1, W2, b2, W3, b3,
                                              fpsIdx, ctr, W1t, W2t, W3t, pos4, ctl,
                                              outX, outP, outB, outS);
  drain_kernel<<<EE, 512, 0, stream>>>(x, pos4, ctr, fpsIdx, W1t, W2t, W3t,
                                       b1, b2, b3, ctl, outX, outP, outB, outS);
}

// Round 13
// 817.885 us; speedup vs baseline: 1.0512x; 1.0512x over previous
//
#include <hip/hip_runtime.h>
#include <stdint.h>

#define BB 8
#define NN 4096
#define CC 64
#define MM 1024
#define EE (BB*MM)   // 8192 centroids
#define KK 64        // max neighbors
#define F3 256       // output channels
#define SM 104       // msg LDS stride (elements)
#define SH 136       // h LDS stride (elements)
#define CAP 768      // candidate buffer

typedef __bf16 bf16x8 __attribute__((ext_vector_type(8)));
typedef float floatx4 __attribute__((ext_vector_type(4)));

// ---- wave64 reductions via DPP (round-3-verified) ----
#define DPP_MAXSTEP(ctrl, rmask) { \
    unsigned o = (unsigned)__builtin_amdgcn_update_dpp(0, (int)v, ctrl, rmask, 0xf, false); \
    v = v > o ? v : o; }
__device__ __forceinline__ unsigned wave_umax_u32(unsigned v) {
  DPP_MAXSTEP(0x111, 0xf)
  DPP_MAXSTEP(0x112, 0xf)
  DPP_MAXSTEP(0x114, 0xf)
  DPP_MAXSTEP(0x118, 0xf)
  DPP_MAXSTEP(0x142, 0xa)
  DPP_MAXSTEP(0x143, 0xc)
  return (unsigned)__builtin_amdgcn_readlane((int)v, 63);
}
#define DPP_MINSTEP(ctrl, rmask) { \
    unsigned o = (unsigned)__builtin_amdgcn_update_dpp((int)0xffffffffu, (int)v, ctrl, rmask, 0xf, false); \
    v = v < o ? v : o; }
__device__ __forceinline__ unsigned wave_umin_u32(unsigned v) {
  DPP_MINSTEP(0x111, 0xf)
  DPP_MINSTEP(0x112, 0xf)
  DPP_MINSTEP(0x114, 0xf)
  DPP_MINSTEP(0x118, 0xf)
  DPP_MINSTEP(0x142, 0xa)
  DPP_MINSTEP(0x143, 0xc)
  return (unsigned)__builtin_amdgcn_readlane((int)v, 63);
}

// ---- MLP item body (round-3-verified numerics; r5/r11-verified refactor) ----
__device__ __forceinline__ void mlp_item(
    int e, int b, int t,
    const float* __restrict__ x, const float4* __restrict__ pos4,
    const float* __restrict__ ctr, const int* __restrict__ fpsIdx,
    const __bf16* __restrict__ W1t, const __bf16* __restrict__ W2t,
    const __bf16* __restrict__ W3t,
    const float* __restrict__ b1, const float* __restrict__ b2,
    const float* __restrict__ b3,
    float* __restrict__ outX, float* __restrict__ outP,
    float* __restrict__ outB, float* __restrict__ outS,
    __bf16* sMsg, __bf16* sH, int* sSel, int* sCnt) {
  // caller must have set *sCnt = 0 and issued __syncthreads()
  unsigned long long* sDI = (unsigned long long*)sMsg;  // [CAP] packed (d2bits<<32 | idx)
  const int lane = t & 63, wv = t >> 6;

  const float cx = ctr[(long)e * 3 + 0];
  const float cy = ctr[(long)e * 3 + 1];
  const float cz = ctr[(long)e * 3 + 2];
  if (t < 3) outP[(long)e * 3 + t] = ctr[(long)e * 3 + t];
  if (t == 3) { outB[e] = (float)b; outS[e] = (float)(b * NN + fpsIdx[e]); }
  const float R2 = (float)(0.2 * 0.2);

  // Phase A: scan 4096 points; ballot-compact candidates to LDS.
#pragma unroll
  for (int q = 0; q < NN / 512; ++q) {
    const int p = t + q * 512;
    const float4 P = pos4[b * NN + p];
    const float dx = __fsub_rn(cx, P.x);
    const float dy = __fsub_rn(cy, P.y);
    const float dz = __fsub_rn(cz, P.z);
    const float d2 = __fadd_rn(__fadd_rn(__fmul_rn(dx, dx), __fmul_rn(dy, dy)), __fmul_rn(dz, dz));
    const bool v = d2 < R2;
    const unsigned long long mask = __ballot(v);
    int wbase = 0;
    if (lane == 0 && mask) wbase = atomicAdd(sCnt, (int)__popcll(mask));
    wbase = __shfl(wbase, 0);
    if (v) {
      const int off = wbase + (int)__popcll(mask & ((1ull << lane) - 1ull));
      if (off < CAP)
        sDI[off] = ((unsigned long long)__float_as_uint(d2) << 32) | (unsigned)p;
    }
  }
  __syncthreads();
  int cnt = *sCnt; cnt = cnt > CAP ? CAP : cnt;
  const int nsel = cnt < KK ? cnt : KK;

  // Phase B: parallel rank selection.
  for (int i = t; i < cnt; i += 512) {
    const unsigned long long my = sDI[i];
    int rank = 0;
#pragma unroll 8
    for (int j = 0; j < cnt; ++j) rank += (sDI[j] < my) ? 1 : 0;
    if (rank < KK) sSel[rank] = (int)(unsigned)(my & 0xffffffffu);
  }
  __syncthreads();
  cnt = nsel;

  // Phase C: stage msg tile into LDS as bf16.
  {
    const int r = t >> 3, p = t & 7;
    float4 a = make_float4(0.f, 0.f, 0.f, 0.f), c4 = a;
    if (r < cnt) {
      const float* xr = x + (long)(b * NN + sSel[r]) * CC + p * 8;
      a  = *(const float4*)xr;
      c4 = *(const float4*)(xr + 4);
    }
    __bf16 o[8] = {(__bf16)a.x, (__bf16)a.y, (__bf16)a.z, (__bf16)a.w,
                   (__bf16)c4.x, (__bf16)c4.y, (__bf16)c4.z, (__bf16)c4.w};
    *(uint4*)&sMsg[r * SM + p * 8] = *(uint4*)o;
  }
  if (t < 64) {
    const int r = t;
    __bf16 d0 = (__bf16)0.0f, d1 = (__bf16)0.0f, d2v = (__bf16)0.0f;
    if (r < cnt) {
      const float4 P = pos4[b * NN + sSel[r]];
      d0  = (__bf16)__fsub_rn(P.x, cx);
      d1  = (__bf16)__fsub_rn(P.y, cy);
      d2v = (__bf16)__fsub_rn(P.z, cz);
    }
    sMsg[r * SM + 64] = d0;
    sMsg[r * SM + 65] = d1;
    sMsg[r * SM + 66] = d2v;
    for (int c = 67; c < SM; ++c) sMsg[r * SM + c] = (__bf16)0.0f;
  }
  __syncthreads();

  const int l15 = lane & 15, quad = lane >> 4;
  // layer 1
  {
    floatx4 acc[4] = {};
    const __bf16* wrow = W1t + (wv * 16 + l15) * 96;
#pragma unroll
    for (int ks = 0; ks < 3; ++ks) {
      const bf16x8 bfrag = *(const bf16x8*)(wrow + ks * 32 + quad * 8);
#pragma unroll
      for (int mt = 0; mt < 4; ++mt) {
        const bf16x8 afrag = *(const bf16x8*)&sMsg[(mt * 16 + l15) * SM + ks * 32 + quad * 8];
        acc[mt] = __builtin_amdgcn_mfma_f32_16x16x32_bf16(afrag, bfrag, acc[mt], 0, 0, 0);
      }
    }
    const int col = wv * 16 + l15;
    const float bias = b1[col];
#pragma unroll
    for (int mt = 0; mt < 4; ++mt)
#pragma unroll
      for (int rg = 0; rg < 4; ++rg) {
        const int row = mt * 16 + quad * 4 + rg;
        float v = acc[mt][rg] + bias;
        v = v > 0.0f ? v : 0.0f;
        sH[row * SH + col] = (__bf16)v;
      }
  }
  __syncthreads();
  // layer 2 (in place on sH)
  {
    floatx4 acc[4] = {};
    const __bf16* wrow = W2t + (wv * 16 + l15) * 128;
#pragma unroll
    for (int ks = 0; ks < 4; ++ks) {
      const bf16x8 bfrag = *(const bf16x8*)(wrow + ks * 32 + quad * 8);
#pragma unroll
      for (int mt = 0; mt < 4; ++mt) {
        const bf16x8 afrag = *(const bf16x8*)&sH[(mt * 16 + l15) * SH + ks * 32 + quad * 8];
        acc[mt] = __builtin_amdgcn_mfma_f32_16x16x32_bf16(afrag, bfrag, acc[mt], 0, 0, 0);
      }
    }
    __syncthreads();
    const int col = wv * 16 + l15;
    const float bias = b2[col];
#pragma unroll
    for (int mt = 0; mt < 4; ++mt)
#pragma unroll
      for (int rg = 0; rg < 4; ++rg) {
        const int row = mt * 16 + quad * 4 + rg;
        float v = acc[mt][rg] + bias;
        v = v > 0.0f ? v : 0.0f;
        sH[row * SH + col] = (__bf16)v;
      }
  }
  __syncthreads();
  // layer 3 + fused masked max
  {
    floatx4 acc[2][4] = {};
#pragma unroll
    for (int ks = 0; ks < 4; ++ks) {
      bf16x8 afrag[4];
#pragma unroll
      for (int mt = 0; mt < 4; ++mt)
        afrag[mt] = *(const bf16x8*)&sH[(mt * 16 + l15) * SH + ks * 32 + quad * 8];
#pragma unroll
      for (int i = 0; i < 2; ++i) {
        const bf16x8 bfrag = *(const bf16x8*)(W3t + ((wv * 2 + i) * 16 + l15) * 128 + ks * 32 + quad * 8);
#pragma unroll
        for (int mt = 0; mt < 4; ++mt)
          acc[i][mt] = __builtin_amdgcn_mfma_f32_16x16x32_bf16(afrag[mt], bfrag, acc[i][mt], 0, 0, 0);
      }
    }
#pragma unroll
    for (int i = 0; i < 2; ++i) {
      const int col = (wv * 2 + i) * 16 + l15;
      const float bias = b3[col];
      float mx = 0.0f;
#pragma unroll
      for (int mt = 0; mt < 4; ++mt)
#pragma unroll
        for (int rg = 0; rg < 4; ++rg) {
          const int row = mt * 16 + quad * 4 + rg;
          float v = acc[i][mt][rg] + bias;
          v = v > 0.0f ? v : 0.0f;
          if (row < cnt) mx = fmaxf(mx, v);
        }
      mx = fmaxf(mx, __shfl_xor(mx, 16));
      mx = fmaxf(mx, __shfl_xor(mx, 32));
      if (quad == 0) outX[(long)e * F3 + col] = mx;
    }
  }
}

// ctl layout (dwords; each counter on its own 128B line); memset 2048 B:
#define CTL_PREP 0
#define CTL_PROG(g) (32*((g)+1))
#define CTL_QHEAD 320
#define CTL_DONE 352

// ---- Kernel A: r11 base (82 KB pad => 1 block/CU; per-iter t0 stores), ONE
//      change: in-loop __syncthreads -> raw `s_waitcnt lgkmcnt(0)` + s_barrier.
//      [HIP-compiler] __syncthreads emits s_waitcnt vmcnt(0) before s_barrier,
//      forcing wave 0 to drain its ctr/fpsIdx stores into a busy L2 every
//      iteration (store-ack ~600-1000cy vs ~450cy of cover = the ~178us
//      residual, if theory (a)). The LDS sRed handoff only needs lgkmcnt.
//      Progress release cadence 32 -> 64 (consumers run behind production, so
//      cadence is invisible; halves the forced-drain cost at the release).
//      If A stays ~750us, the residual is DVFS -> revert to r11 and stop.
__global__ __launch_bounds__(512) void fps_overlap_kernel(
    const float* __restrict__ x, const float* __restrict__ pos,
    const float* __restrict__ W1, const float* __restrict__ b1,
    const float* __restrict__ W2, const float* __restrict__ b2,
    const float* __restrict__ W3, const float* __restrict__ b3,
    int* __restrict__ fpsIdx, float* __restrict__ ctr,
    __bf16* __restrict__ W1t, __bf16* __restrict__ W2t, __bf16* __restrict__ W3t,
    float4* __restrict__ pos4, unsigned* __restrict__ ctl,
    float* __restrict__ outX, float* __restrict__ outP,
    float* __restrict__ outB, float* __restrict__ outS) {
  __shared__ __align__(16) unsigned char sBuf[83968];  // 82 KB pad => exclusive CU
  __shared__ int sClaim;

  const int t = threadIdx.x;
  const int blk = blockIdx.x;

  if (blk < BB) {
    // ================= FPS producer (graph g), r3-exact 4-wave loop =================
    const int g = blk;
    float4* sP4 = (float4*)sBuf;
    unsigned long long* sRed = (unsigned long long*)(sBuf + 65536);  // [2][4]

    // prep slice: 94208 items over 8 blocks = 11776 each
    for (int k = g * 11776 + t; k < (g + 1) * 11776; k += 512) {
      if (k < 12288) {
        const int n = k / 96, kk = k % 96;
        W1t[k] = (kk < 67) ? (__bf16)W1[kk * 128 + n] : (__bf16)0.0f;
      } else if (k < 28672) {
        const int i = k - 12288, n = i / 128, kk = i % 128;
        W2t[i] = (__bf16)W2[kk * 128 + n];
      } else if (k < 61440) {
        const int i = k - 28672, n = i / 128, kk = i % 128;
        W3t[i] = (__bf16)W3[kk * 256 + n];
      } else {
        const int i = k - 61440;
        pos4[i] = make_float4(pos[(long)i * 3 + 0], pos[(long)i * 3 + 1],
                              pos[(long)i * 3 + 2], 0.0f);
      }
    }
    __threadfence();
    __syncthreads();
    if (t == 0)
      __hip_atomic_fetch_add(&ctl[CTL_PREP], 1u, __ATOMIC_RELEASE, __HIP_MEMORY_SCOPE_AGENT);

    __builtin_amdgcn_s_setprio(1);

    const int lane = t & 63, wv = t >> 6;    // working waves 0..3 (t<256)
    float px[16], py[16], pz[16], mind[16];
    if (t < 256) {
#pragma unroll
      for (int j = 0; j < 16; ++j) {
        const int p = t + (j << 8);
        const long base = ((long)g * NN + p) * 3;
        px[j] = pos[base + 0];
        py[j] = pos[base + 1];
        pz[j] = pos[base + 2];
        mind[j] = 1e10f;
        sP4[p] = make_float4(px[j], py[j], pz[j], 0.0f);
      }
    }
    __syncthreads();
    float wx = 0.f, wy = 0.f, wz = 0.f;
    if (t < 256) { const float4 w0 = sP4[0]; wx = w0.x; wy = w0.y; wz = w0.z; }
    if (t == 0) {                            // sample 0 = point 0
      const long e0 = (long)g * MM;
      ctr[e0 * 3 + 0] = wx; ctr[e0 * 3 + 1] = wy; ctr[e0 * 3 + 2] = wz;
      fpsIdx[e0] = 0;
    }
    for (int s = 1; s < MM; ++s) {
      if (t < 256) {
        // --- inner: exact r3 numerics ---
        unsigned bb = 0u, bidx = (unsigned)t;
#pragma unroll
        for (int j = 0; j < 16; ++j) {
          const float dx = __fsub_rn(px[j], wx);
          const float dy = __fsub_rn(py[j], wy);
          const float dz = __fsub_rn(pz[j], wz);
          const float d2 = __fadd_rn(__fadd_rn(__fmul_rn(dx, dx), __fmul_rn(dy, dy)), __fmul_rn(dz, dz));
          mind[j] = fminf(mind[j], d2);
          const unsigned mb = __float_as_uint(mind[j]);
          if (mb > bb) { bb = mb; bidx = (unsigned)(t + (j << 8)); }
        }
        const unsigned maxv = wave_umax_u32(bb);
        const unsigned cand = (bb == maxv) ? bidx : 0xffffffffu;
        const unsigned widx_w = wave_umin_u32(cand);
        if (lane == 0)
          sRed[(s & 1) * 4 + wv] = ((unsigned long long)maxv << 32) | (unsigned long long)(~widx_w);
      }
      // Raw barrier: drain LDS only (sRed handoff); leave t0's global stores
      // in flight across the barrier (vmcnt depth 63 >> 4 stores/iter).
      __asm__ __volatile__("s_waitcnt lgkmcnt(0)" ::: "memory");
      __builtin_amdgcn_s_barrier();
      if (t < 256) {
        unsigned long long m = sRed[(s & 1) * 4 + 0];
#pragma unroll
        for (int w = 1; w < 4; ++w) {
          const unsigned long long o = sRed[(s & 1) * 4 + w];
          m = o > m ? o : m;
        }
        const int widx = (int)(~(unsigned)m);
        const float4 wp = sP4[widx];
        wx = wp.x; wy = wp.y; wz = wp.z;
        if (t == 0) {                        // stream centroid s out (lazy drain)
          const long eo = (long)g * MM + s;
          ctr[eo * 3 + 0] = wp.x; ctr[eo * 3 + 1] = wp.y; ctr[eo * 3 + 2] = wp.z;
          fpsIdx[eo] = widx;
          if ((s & 63) == 63)                // publish every 64 (release orders prior stores)
            __hip_atomic_store(&ctl[CTL_PROG(g)], (unsigned)(s + 1),
                               __ATOMIC_RELEASE, __HIP_MEMORY_SCOPE_AGENT);
        }
      }
    }
    __syncthreads();
    if (t == 0) {
      __hip_atomic_store(&ctl[CTL_PROG(g)], 1024u,
                         __ATOMIC_RELEASE, __HIP_MEMORY_SCOPE_AGENT);
      __hip_atomic_fetch_add(&ctl[CTL_DONE], 1u, __ATOMIC_RELEASE, __HIP_MEMORY_SCOPE_AGENT);
    }
    return;
  }

  // ================= persistent MLP worker (exclusive CU) =================
  {
    __bf16* sMsg = (__bf16*)sBuf;
    __bf16* sH   = (__bf16*)(sBuf + 13312);
    int* sSel    = (int*)(sBuf + 30720);
    int* sCnt    = (int*)(sBuf + 30976);

    if (t == 0) {  // weights/pos4 gate (once)
      while (__hip_atomic_load(&ctl[CTL_PREP], __ATOMIC_ACQUIRE, __HIP_MEMORY_SCOPE_AGENT) < (unsigned)BB)
        __builtin_amdgcn_s_sleep(8);
    }
    __syncthreads();

    for (;;) {
      if (t == 0) {
        unsigned c;
        const unsigned dn = __hip_atomic_load(&ctl[CTL_DONE], __ATOMIC_ACQUIRE, __HIP_MEMORY_SCOPE_AGENT);
        if (dn >= (unsigned)BB) c = EE;          // FPS done: stop claiming; drain finishes rest
        else c = __hip_atomic_fetch_add(&ctl[CTL_QHEAD], 1u, __ATOMIC_RELAXED, __HIP_MEMORY_SCOPE_AGENT);
        sClaim = (int)c;
      }
      __syncthreads();
      const int c = sClaim;
      if (c >= EE) return;
      const int g = c & 7, sidx = c >> 3;        // interleave across graphs = production order
      const int e = g * MM + sidx;
      if (t == 0) {
        while (__hip_atomic_load(&ctl[CTL_PROG(g)], __ATOMIC_ACQUIRE, __HIP_MEMORY_SCOPE_AGENT)
               <= (unsigned)sidx)
          __builtin_amdgcn_s_sleep(8);
        *sCnt = 0;
      }
      __syncthreads();
      mlp_item(e, g, t, x, pos4, ctr, fpsIdx, W1t, W2t, W3t, b1, b2, b3,
               outX, outP, outB, outS, sMsg, sH, sSel, sCnt);
      // loop-top barrier re-joins all threads before LDS reuse
    }
  }
}

// ---- Kernel B: drain remaining items (runs after A completes; no spins) ----
__global__ __launch_bounds__(512) void drain_kernel(
    const float* __restrict__ x, const float4* __restrict__ pos4,
    const float* __restrict__ ctr, const int* __restrict__ fpsIdx,
    const __bf16* __restrict__ W1t, const __bf16* __restrict__ W2t,
    const __bf16* __restrict__ W3t,
    const float* __restrict__ b1, const float* __restrict__ b2,
    const float* __restrict__ b3, unsigned* __restrict__ ctl,
    float* __restrict__ outX, float* __restrict__ outP,
    float* __restrict__ outB, float* __restrict__ outS) {
  __shared__ __align__(16) __bf16 sMsg[64 * SM];
  __shared__ __align__(16) __bf16 sH[64 * SH];
  __shared__ int sSel[KK];
  __shared__ int sCnt;
  __shared__ int sClaim;
  const int t = threadIdx.x;

  if (t == 0) {
    unsigned c = __hip_atomic_load(&ctl[CTL_QHEAD], __ATOMIC_RELAXED, __HIP_MEMORY_SCOPE_AGENT);
    if (c < (unsigned)EE)   // shortcut avoids atomic herd once queue exhausted
      c = __hip_atomic_fetch_add(&ctl[CTL_QHEAD], 1u, __ATOMIC_RELAXED, __HIP_MEMORY_SCOPE_AGENT);
    sClaim = (int)c;
    sCnt = 0;
  }
  __syncthreads();
  const int c = sClaim;
  if (c >= EE) return;
  const int g = c & 7, sidx = c >> 3;
  mlp_item(g * MM + sidx, g, t, x, pos4, ctr, fpsIdx, W1t, W2t, W3t, b1, b2, b3,
           outX, outP, outB, outS, sMsg, sH, sSel, &sCnt);
}

extern "C" void kernel_launch(void* const* d_in, const int* in_sizes, int n_in,
                              void* d_out, int out_size, void* d_ws, size_t ws_size,
                              hipStream_t stream) {
  const float* x   = (const float*)d_in[0];
  const float* pos = (const float*)d_in[1];
  const float* W1  = (const float*)d_in[4];
  const float* b1  = (const float*)d_in[5];
  const float* W2  = (const float*)d_in[6];
  const float* b2  = (const float*)d_in[7];
  const float* W3  = (const float*)d_in[8];
  const float* b3  = (const float*)d_in[9];

  // Workspace layout (~781 KB)
  char* ws = (char*)d_ws;
  int*    fpsIdx = (int*)(ws);                 // 32768              (ends 32768)
  float*  ctr    = (float*)(ws + 32768);       // 98304              (ends 131072)
  __bf16* W1t    = (__bf16*)(ws + 131072);     // 24576              (ends 155648)
  __bf16* W2t    = (__bf16*)(ws + 155648);     // 32768              (ends 188416)
  __bf16* W3t    = (__bf16*)(ws + 188416);     // 65536              (ends 253952)
  float4* pos4   = (float4*)(ws + 253952);     // 524288             (ends 778240)
  unsigned* ctl  = (unsigned*)(ws + 778240);   // 2048               (ends 780288)

  float* outX = (float*)d_out;                 // [8192,256]
  float* outP = outX + (long)EE * F3;          // [8192,3]
  float* outB = outP + (long)EE * 3;           // [8192]
  float* outS = outB + EE;                     // [8192]

  hipMemsetAsync(ctl, 0, 2048, stream);
  fps_overlap_kernel<<<256, 512, 0, stream>>>(x, pos, W1, b1, W2, b2, W3, b3,
                                              fpsIdx, ctr, W1t, W2t, W3t, pos4, ctl,
                                              outX, outP, outB, outS);
  drain_kernel<<<EE, 512, 0, stream>>>(x, pos4, ctr, fpsIdx, W1t, W2t, W3t,
                                       b1, b2, b3, ctl, outX, outP, outB, outS);
}